// Round 11
// baseline (483.355 us; speedup 1.0000x reference)
//
#include <hip/hip_runtime.h>

#define BATCH 32
#define TIME  512
#define INF   512
#define HIDF  1024

#define RPW  16          // bt rows per wave
#define NBH  64          // h cols per block (= lane count)
#define KCH  16          // k per chunk
#define NCH  (INF / KCH) // 32 chunks
#define WPAD 65          // ws row stride: 64 + 1 (2-way max on b32 reads = free)

// ---------------------------------------------------------------------------
// Phase 1: hidden[bt][h] = (sum_k x[bt,k]*W[h,k]) + bias[h], bit-exact vs the
// XLA canonical order (verified R3): ONE fp32 accumulator per output, fused
// FMA, k strictly ascending, ONE fp32 rounding for +bias.
//
// R10 post-mortem: the symmetric LDS-tile structure stalls ~50% per chunk
// (both FMA operands LDS-sourced, low occupancy). Restructure: lane <-> h.
//   - x[bt,k] is wave-uniform -> s_load (SMEM pipe), feeds FMA as the SGPR
//     operand. No LDS, no VALU, no VMEM for x in the inner loop.
//   - W staged 64h x 16k per chunk via one float4/thread, written transposed
//     ws[k][h] (pad 65); lane reads ws[k][lane] = consecutive banks.
//   - acc=16 VGPRs -> ~full occupancy (8 blocks/CU), latency drowned in waves.
// ---------------------------------------------------------------------------
__global__ __launch_bounds__(256)
void snn_gemm_seqfma(const float* __restrict__ x, const float* __restrict__ W,
                     const float* __restrict__ bias, float* __restrict__ hidden) {
    __shared__ __align__(16) float ws[KCH * WPAD];   // 4160 B

    const int tid  = threadIdx.x;
    const int lane = tid & 63;
    const int wv   = __builtin_amdgcn_readfirstlane(tid >> 6);  // wave 0..3
    const int h0   = blockIdx.x * NBH;
    const int bt0  = blockIdx.y * 64 + wv * RPW;    // this wave's 16 bt rows

    // staging: thread loads W[h0 + tid/4][kc*16 + (tid&3)*4 .. +3]
    const int sh = tid >> 2;         // 0..63
    const int sq = tid & 3;          // k-quad within chunk
    const float* wg = W + (size_t)(h0 + sh) * INF + sq * 4;

    float acc[RPW];
    #pragma unroll
    for (int r = 0; r < RPW; ++r) acc[r] = 0.0f;

    float4 wch = *(const float4*)wg;                // prefetch chunk 0

    for (int kc = 0; kc < NCH; ++kc) {
        // ---- write staged chunk, transposed ws[k][h] ----
        ws[(sq * 4 + 0) * WPAD + sh] = wch.x;
        ws[(sq * 4 + 1) * WPAD + sh] = wch.y;
        ws[(sq * 4 + 2) * WPAD + sh] = wch.z;
        ws[(sq * 4 + 3) * WPAD + sh] = wch.w;
        __syncthreads();

        // ---- prefetch next chunk's W (consumed just before next barrier) ----
        if (kc + 1 < NCH)
            wch = *(const float4*)(wg + (kc + 1) * KCH);

        // ---- compute: x via wave-uniform s_load, W from LDS ----
        const float* xb = x + (size_t)bt0 * INF + kc * KCH;   // uniform
        #pragma unroll
        for (int g = 0; g < 4; ++g) {
            const int kl = g * 4;
            float w0 = ws[(kl + 0) * WPAD + lane];
            float w1 = ws[(kl + 1) * WPAD + lane];
            float w2 = ws[(kl + 2) * WPAD + lane];
            float w3 = ws[(kl + 3) * WPAD + lane];
            #pragma unroll
            for (int r = 0; r < RPW; ++r) {
                float4 xv = *(const float4*)(xb + r * INF + kl);  // s_load_dwordx4
                // k strictly ascending for every output chain
                acc[r] = __fmaf_rn(xv.x, w0, acc[r]);
                acc[r] = __fmaf_rn(xv.y, w1, acc[r]);
                acc[r] = __fmaf_rn(xv.z, w2, acc[r]);
                acc[r] = __fmaf_rn(xv.w, w3, acc[r]);
            }
        }
        __syncthreads();
    }

    // ---- epilogue: one fp32 rounding for bias; coalesced 256 B stores ----
    const float bv = bias[h0 + lane];
    #pragma unroll
    for (int r = 0; r < RPW; ++r)
        hidden[(size_t)(bt0 + r) * HIDF + h0 + lane] = __fadd_rn(acc[r], bv);
}

// ---------------------------------------------------------------------------
// Phase 2: in-place LIF scan over t per (b,h) column, fp32:
//   mem = fl32(0.5*mem + h_t); spk = mem > 1.0f; hard reset to 0.
// 1 thread/column (512 waves = 2/CU); next burst prefetched before the
// current burst's stores so HBM latency overlaps compute+stores.
// ---------------------------------------------------------------------------
__global__ __launch_bounds__(256)
void snn_scan_np(float* __restrict__ io) {
    const int n = blockIdx.x * 256 + threadIdx.x;   // 0..32767
    const int b = n >> 10;
    const int h = n & 1023;
    float* p = io + (size_t)b * TIME * HIDF + h;

    float cur[16], nxt[16];
    #pragma unroll
    for (int u = 0; u < 16; ++u) cur[u] = p[(size_t)u * HIDF];

    float mem = 0.0f;
    for (int tb = 0; tb < TIME / 16; ++tb) {
        if (tb + 1 < TIME / 16) {
            #pragma unroll
            for (int u = 0; u < 16; ++u)
                nxt[u] = p[(size_t)((tb + 1) * 16 + u) * HIDF];
        }
        float sp[16];
        #pragma unroll
        for (int u = 0; u < 16; ++u) {
            mem = __fadd_rn(__fmul_rn(0.5f, mem), cur[u]);
            bool s = mem > 1.0f;
            sp[u] = s ? 1.0f : 0.0f;
            if (s) mem = 0.0f;
        }
        #pragma unroll
        for (int u = 0; u < 16; ++u) p[(size_t)(tb * 16 + u) * HIDF] = sp[u];
        #pragma unroll
        for (int u = 0; u < 16; ++u) cur[u] = nxt[u];
    }
}

extern "C" void kernel_launch(void* const* d_in, const int* in_sizes, int n_in,
                              void* d_out, int out_size, void* d_ws, size_t ws_size,
                              hipStream_t stream) {
    const float* x    = (const float*)d_in[0];   // [32, 512, 512]
    const float* W    = (const float*)d_in[1];   // [1024, 512]
    const float* bias = (const float*)d_in[2];   // [1024]
    float* out = (float*)d_out;                  // [32, 512, 1024]

    dim3 g1(HIDF / NBH, (BATCH * TIME) / 64);    // (16, 256) = 4096 blocks
    snn_gemm_seqfma<<<g1, 256, 0, stream>>>(x, W, bias, out);

    snn_scan_np<<<(BATCH * HIDF) / 256, 256, 0, stream>>>(out);
}